// Round 8
// baseline (443.775 us; speedup 1.0000x reference)
//
#include <hip/hip_runtime.h>
#include <hip/hip_bf16.h>

// clusterLayer: q = rownorm( 1 / (1 + ||x||^2 + ||c||^2 - 2 x.cT) )
// N=524288, K=256, D=256. fp32 in/out.
// Kernel 0: clusters fp32 -> bf16 in 32x32x16-MFMA-fragment order
//   (1 KiB per (nj,ks) fragment) + fp32 c2 norms, in d_ws.
// Main: persistent blocks, NT=8 M-tiles each, cross-tile pipeline:
//   A-loads for tile t+1 issued right after tile t's K-loop (FIFO-safe:
//   after all B issues), convert+ds_write into double-buffered Af after
//   pass2. Staging HBM latency hidden under epilogue; staging is off the
//   serial path. 2 barriers/tile. BM=32, 4 waves = 4 col-quarters.

#define DD 256
#define KC 256
#define BM 32
#define NT 8                           // tiles per block
#define CL_SHORTS (KC * DD)            // 65536 shorts = 131072 B

typedef __attribute__((ext_vector_type(4)))  float f32x4;
typedef __attribute__((ext_vector_type(16))) float f32x16;
typedef __attribute__((ext_vector_type(8)))  short bf16x8;
typedef __attribute__((ext_vector_type(4)))  short bf16x4;

__device__ __forceinline__ short f2bf(float f) {
    union { float f; unsigned u; } v; v.f = f;
    unsigned r = (v.u + 0x7fffu + ((v.u >> 16) & 1u)) >> 16;
    return (short)r;
}

__device__ __forceinline__ f32x4 ld4(const float* p) { return *(const f32x4*)p; }

// ---------------- Kernel 0: prep clusters (fragment-order bf16 + norms) ----
__global__ __launch_bounds__(64)
void prep_clusters(const float* __restrict__ clus,
                   short* __restrict__ wsb, float* __restrict__ c2) {
    const int c = blockIdx.x;      // cluster row 0..255
    const int t = threadIdx.x;     // 0..63, 4 floats each
    f32x4 v = *(const f32x4*)(clus + c * DD + t * 4);
    bf16x4 o;
    o[0] = f2bf(v[0]); o[1] = f2bf(v[1]); o[2] = f2bf(v[2]); o[3] = f2bf(v[3]);

    // fragment layout: frag(nj,ks) = 512 contiguous shorts; within it,
    // lane (hi*32+l31) holds clusters[nj*32+l31][ks*16+hi*8 .. +8].
    const int j    = t >> 1;       // 8-elem chunk index within row (k/8)
    const int ks   = j >> 1;
    const int hi   = j & 1;
    const int half = t & 1;        // which 4-elem half of the chunk
    const int nj   = c >> 5;
    const int l31  = c & 31;
    *(bf16x4*)&wsb[(((nj * 16 + ks) * 64 + hi * 32 + l31) << 3) + half * 4] = o;

    float s = v[0]*v[0] + v[1]*v[1] + v[2]*v[2] + v[3]*v[3];
    s += __shfl_xor(s, 1);  s += __shfl_xor(s, 2);  s += __shfl_xor(s, 4);
    s += __shfl_xor(s, 8);  s += __shfl_xor(s, 16); s += __shfl_xor(s, 32);
    if (t == 0) c2[c] = s;
}

// ---------------- Main kernel ----------------
__global__ __launch_bounds__(256, 3)
void cluster_q_main(const float* __restrict__ ctx,
                    const short* __restrict__ wsb,
                    const float* __restrict__ c2g,
                    float* __restrict__ out) {
    __shared__ short Af[2][32 * 32 * 8];   // 2 x 16 KiB, [buf][j=k/8][row][8]
    __shared__ float x2p4[2][4][BM];       // per-(buf,wave,row) |x|^2 partials
    __shared__ float rowsum[4][BM];        // per-(quarter,row) q-sums

    const int t    = threadIdx.x;
    const int lane = t & 63;
    const int w    = t >> 6;               // wave = col-quarter 0..3
    const int l31  = lane & 31;
    const int hi   = lane >> 5;
    const int r_st    = lane >> 1;         // staging: row 0..31
    const int half_st = lane & 1;          // staging: 32-float half

    const size_t row_blk = (size_t)blockIdx.x * (NT * BM);

    // B fragment base: col-tile njg = w*2 + j2, frag (njg*16+ks)*512
    const short* bl = wsb + (size_t)(w * 2 * 16) * 512 + lane * 8;
    float c2v[2];
    c2v[0] = c2g[w * 64 + l31];
    c2v[1] = c2g[w * 64 + 32 + l31];

    const float* srcbase = ctx + (row_blk + (size_t)r_st) * DD + w * 64 + half_st * 32;

    f32x4 u[8];

    // ---- prologue: stage tile 0 ----
#pragma unroll
    for (int i = 0; i < 4; ++i) {
        u[2*i]   = ld4(srcbase + i * 8);
        u[2*i+1] = ld4(srcbase + i * 8 + 4);
    }
    {
        float xs = 0.f;
#pragma unroll
        for (int i = 0; i < 4; ++i) {
            f32x4 a0 = u[2*i], a1 = u[2*i+1];
            bf16x8 o;
            o[0] = f2bf(a0[0]); o[1] = f2bf(a0[1]);
            o[2] = f2bf(a0[2]); o[3] = f2bf(a0[3]);
            o[4] = f2bf(a1[0]); o[5] = f2bf(a1[1]);
            o[6] = f2bf(a1[2]); o[7] = f2bf(a1[3]);
            xs += a0[0]*a0[0] + a0[1]*a0[1] + a0[2]*a0[2] + a0[3]*a0[3]
                + a1[0]*a1[0] + a1[1]*a1[1] + a1[2]*a1[2] + a1[3]*a1[3];
            const int j = w * 8 + half_st * 4 + i;
            *(bf16x8*)&Af[0][(j * 32 + r_st) * 8] = o;
        }
        xs += __shfl_xor(xs, 1);
        if (half_st == 0) x2p4[0][w][r_st] = xs;
    }
    __syncthreads();

#pragma unroll 2
    for (int it = 0; it < NT; ++it) {
        const int cur = it & 1;
        const int nxt = cur ^ 1;
        const size_t trow = row_blk + (size_t)it * BM;

        const float x2l = x2p4[cur][0][l31] + x2p4[cur][1][l31]
                        + x2p4[cur][2][l31] + x2p4[cur][3][l31];

        f32x16 acc[2];
        acc[0] = (f32x16)0.f;
        acc[1] = (f32x16)0.f;

        const short* AfC = &Af[cur][0];

        // B: 3-slot rotation, distance 2 (slot p holds step p at start)
        bf16x8 bs[3][2];
#pragma unroll
        for (int p = 0; p < 2; ++p)
#pragma unroll
            for (int j2 = 0; j2 < 2; ++j2)
                bs[p][j2] = *(const bf16x8*)(bl + (j2 * 16 + p) * 512);

        // A-frag: 3-slot rotation, distance 2 (LDS)
        bf16x8 af[3];
        af[0] = *(const bf16x8*)&AfC[((0 * 2 + hi) * 32 + l31) * 8];
        af[1] = *(const bf16x8*)&AfC[((1 * 2 + hi) * 32 + l31) * 8];

#pragma unroll
        for (int ks = 0; ks < 16; ++ks) {
            const int cA = ks % 3;               // consume slot (== issue map)
            if (ks < 14) {
                const int nx = (ks + 2) % 3;
#pragma unroll
                for (int j2 = 0; j2 < 2; ++j2)
                    bs[nx][j2] = *(const bf16x8*)(bl + (j2 * 16 + ks + 2) * 512);
                af[nx] = *(const bf16x8*)&AfC[(((ks + 2) * 2 + hi) * 32 + l31) * 8];
            }
#pragma unroll
            for (int j2 = 0; j2 < 2; ++j2)
                acc[j2] = __builtin_amdgcn_mfma_f32_32x32x16_bf16(
                    af[cA], bs[cA][j2], acc[j2], 0, 0, 0);
        }

        // ---- issue next-tile A loads (after ALL B issues -> FIFO-safe;
        //      latency hides under pass1/pass2) ----
        if (it + 1 < NT) {
            const float* s2 = srcbase + (size_t)(it + 1) * BM * DD;
#pragma unroll
            for (int i = 0; i < 4; ++i) {
                u[2*i]   = ld4(s2 + i * 8);
                u[2*i+1] = ld4(s2 + i * 8 + 4);
            }
        }

        // ---- pass 1: q = 1/(1+d), per-row partial sums -> LDS ----
#pragma unroll
        for (int r = 0; r < 16; ++r) {
            const int rr = (r & 3) + 8 * (r >> 2) + 4 * hi;   // row 0..31
            const float x2r = __shfl(x2l, rr);
            float s = 0.f;
#pragma unroll
            for (int j2 = 0; j2 < 2; ++j2) {
                float d = x2r + c2v[j2] - 2.f * acc[j2][r];
                float q = 1.f / (1.f + d);
                acc[j2][r] = q;
                s += q;
            }
            s += __shfl_xor(s, 1);
            s += __shfl_xor(s, 2);
            s += __shfl_xor(s, 4);
            s += __shfl_xor(s, 8);
            s += __shfl_xor(s, 16);
            if (l31 == 0) rowsum[w][rr] = s;
        }
        __syncthreads();

        // ---- pass 2: normalize + full-line stores ----
#pragma unroll
        for (int r = 0; r < 16; ++r) {
            const int rr = (r & 3) + 8 * (r >> 2) + 4 * hi;
            const float inv = 1.f / (rowsum[0][rr] + rowsum[1][rr] +
                                     rowsum[2][rr] + rowsum[3][rr]);
            float* op = out + (trow + (size_t)rr) * KC + w * 64 + l31;
#pragma unroll
            for (int j2 = 0; j2 < 2; ++j2)
                op[j2 * 32] = acc[j2][r] * inv;   // 2 x 128-B full lines
        }

        // ---- convert + publish tile it+1 into Af[nxt] ----
        if (it + 1 < NT) {
            float xs = 0.f;
#pragma unroll
            for (int i = 0; i < 4; ++i) {
                f32x4 a0 = u[2*i], a1 = u[2*i+1];
                bf16x8 o;
                o[0] = f2bf(a0[0]); o[1] = f2bf(a0[1]);
                o[2] = f2bf(a0[2]); o[3] = f2bf(a0[3]);
                o[4] = f2bf(a1[0]); o[5] = f2bf(a1[1]);
                o[6] = f2bf(a1[2]); o[7] = f2bf(a1[3]);
                xs += a0[0]*a0[0] + a0[1]*a0[1] + a0[2]*a0[2] + a0[3]*a0[3]
                    + a1[0]*a1[0] + a1[1]*a1[1] + a1[2]*a1[2] + a1[3]*a1[3];
                const int j = w * 8 + half_st * 4 + i;
                *(bf16x8*)&Af[nxt][(j * 32 + r_st) * 8] = o;
            }
            xs += __shfl_xor(xs, 1);
            if (half_st == 0) x2p4[nxt][w][r_st] = xs;
        }
        __syncthreads();
    }
}

extern "C" void kernel_launch(void* const* d_in, const int* in_sizes, int n_in,
                              void* d_out, int out_size, void* d_ws, size_t ws_size,
                              hipStream_t stream) {
    const float* ctx  = (const float*)d_in[0];
    const float* clus = (const float*)d_in[1];
    float* out = (float*)d_out;

    short* wsb = (short*)d_ws;                               // bf16 fragment image
    float* c2  = (float*)((char*)d_ws + CL_SHORTS * 2);      // 256 fp32 norms

    const int nrows = in_sizes[0] / DD;                      // 524288
    const int grid  = nrows / (BM * NT);                     // 2048

    hipLaunchKernelGGL(prep_clusters, dim3(KC), dim3(64), 0, stream, clus, wsb, c2);
    hipLaunchKernelGGL(cluster_q_main, dim3(grid), dim3(256), 0, stream,
                       ctx, wsb, c2, out);
}

// Round 9
// 271.793 us; speedup vs baseline: 1.6328x; 1.6328x over previous
//
#include <hip/hip_runtime.h>
#include <hip/hip_bf16.h>

// clusterLayer: q = rownorm( 1 / (1 + ||x||^2 + ||c||^2 - 2 x.cT) )
// N=524288, K=256, D=256. fp32 in/out.
// Kernel 0: clusters fp32 -> bf16 in 32x32x16-MFMA-fragment order
//   (1 KiB per (nj,ks) fragment) + fp32 c2 norms, in d_ws.
// Main (r7 structure, BM=32, 4 waves = 4 col-quarters):
//   - A converted to bf16 once per block into 16-KiB LDS (fragment order).
//   - K-loop: ds_read_b128 A (3-slot/d2) + 2 global B-frags (L2-hot,
//     3-slot/d2) + 2 MFMA.
//   - VALU diet vs r7: v_cvt_pk_bf16_f32 for fp32->bf16 (16 ops vs 128),
//     v_rcp_f32 for all reciprocals (48 divides -> 48 rcp).
//   - launch_bounds(256,6): 6 blocks/CU (LDS 104 KiB), reg cap 85.

#define DD 256
#define KC 256
#define BM 32
#define CL_SHORTS (KC * DD)            // 65536 shorts = 131072 B

typedef __attribute__((ext_vector_type(4)))  float f32x4;
typedef __attribute__((ext_vector_type(16))) float f32x16;
typedef __attribute__((ext_vector_type(8)))  short bf16x8;
typedef __attribute__((ext_vector_type(4)))  short bf16x4;
typedef __attribute__((ext_vector_type(4)))  unsigned u32x4;

__device__ __forceinline__ short f2bf(float f) {
    union { float f; unsigned u; } v; v.f = f;
    unsigned r = (v.u + 0x7fffu + ((v.u >> 16) & 1u)) >> 16;
    return (short)r;
}

// packed fp32->bf16 RNE: dst.lo = cvt(a), dst.hi = cvt(b)
__device__ __forceinline__ unsigned cvtpk(float a, float b) {
    unsigned r;
    asm("v_cvt_pk_bf16_f32 %0, %1, %2" : "=v"(r) : "v"(a), "v"(b));
    return r;
}

__device__ __forceinline__ float frcp(float x) {
    return __builtin_amdgcn_rcpf(x);
}

__device__ __forceinline__ f32x4 ld4(const float* p) { return *(const f32x4*)p; }

// ---------------- Kernel 0: prep clusters (fragment-order bf16 + norms) ----
__global__ __launch_bounds__(64)
void prep_clusters(const float* __restrict__ clus,
                   short* __restrict__ wsb, float* __restrict__ c2) {
    const int c = blockIdx.x;      // cluster row 0..255
    const int t = threadIdx.x;     // 0..63, 4 floats each
    f32x4 v = *(const f32x4*)(clus + c * DD + t * 4);
    bf16x4 o;
    o[0] = f2bf(v[0]); o[1] = f2bf(v[1]); o[2] = f2bf(v[2]); o[3] = f2bf(v[3]);

    // fragment layout: frag(nj,ks) = 512 contiguous shorts; within it,
    // lane (hi*32+l31) holds clusters[nj*32+l31][ks*16+hi*8 .. +8].
    const int j    = t >> 1;       // 8-elem chunk index within row (k/8)
    const int ks   = j >> 1;
    const int hi   = j & 1;
    const int half = t & 1;        // which 4-elem half of the chunk
    const int nj   = c >> 5;
    const int l31  = c & 31;
    *(bf16x4*)&wsb[(((nj * 16 + ks) * 64 + hi * 32 + l31) << 3) + half * 4] = o;

    float s = v[0]*v[0] + v[1]*v[1] + v[2]*v[2] + v[3]*v[3];
    s += __shfl_xor(s, 1);  s += __shfl_xor(s, 2);  s += __shfl_xor(s, 4);
    s += __shfl_xor(s, 8);  s += __shfl_xor(s, 16); s += __shfl_xor(s, 32);
    if (t == 0) c2[c] = s;
}

// ---------------- Main kernel ----------------
__global__ __launch_bounds__(256, 6)
void cluster_q_main(const float* __restrict__ ctx,
                    const short* __restrict__ wsb,
                    const float* __restrict__ c2g,
                    float* __restrict__ out) {
    __shared__ short Af[32 * 32 * 8];    // 16 KiB: [j=k/8][row][8 shorts]
    __shared__ float x2p4[4][BM];        // per-(wave,row) |x|^2 partials
    __shared__ float rowsum[4][BM];      // per-(quarter,row) q-sums

    const int t    = threadIdx.x;
    const int lane = t & 63;
    const int w    = t >> 6;             // wave = col-quarter 0..3
    const int l31  = lane & 31;
    const int hi   = lane >> 5;
    const size_t row0 = (size_t)blockIdx.x * BM;

    // ---- stage A: wave w converts k-range [w*64, w*64+64) of all 32 rows ----
    {
        const int r    = lane >> 1;      // row 0..31
        const int half = lane & 1;       // 32-float half of the quarter
        const float* src = ctx + (row0 + (size_t)r) * DD + w * 64 + half * 32;
        f32x4 u[8];
#pragma unroll
        for (int i = 0; i < 4; ++i) {    // 8 independent loads, all in flight
            u[2*i]   = ld4(src + i * 8);
            u[2*i+1] = ld4(src + i * 8 + 4);
        }
        float xs = 0.f;
#pragma unroll
        for (int i = 0; i < 4; ++i) {
            f32x4 a0 = u[2*i], a1 = u[2*i+1];
            u32x4 o;
            o[0] = cvtpk(a0[0], a0[1]);
            o[1] = cvtpk(a0[2], a0[3]);
            o[2] = cvtpk(a1[0], a1[1]);
            o[3] = cvtpk(a1[2], a1[3]);
            xs += a0[0]*a0[0] + a0[1]*a0[1] + a0[2]*a0[2] + a0[3]*a0[3]
                + a1[0]*a1[0] + a1[1]*a1[1] + a1[2]*a1[2] + a1[3]*a1[3];
            const int j = w * 8 + half * 4 + i;          // k/8 chunk index
            *(u32x4*)&Af[(j * 32 + r) * 8] = o;
        }
        xs += __shfl_xor(xs, 1);                         // combine halves
        if (half == 0) x2p4[w][r] = xs;
    }

    // B fragment base: global col-tile njg = w*2 + j2, frag (njg*16+ks)*512
    const short* bl = wsb + (size_t)(w * 2 * 16) * 512 + lane * 8;

    // hoisted c2 loads (L2-hot; latency hides under K-loop)
    float c2v[2];
    c2v[0] = c2g[w * 64 + l31];
    c2v[1] = c2g[w * 64 + 32 + l31];

    __syncthreads();

    // |x|^2 total for row l31 (conflict-free stride-4 reads)
    const float x2l = x2p4[0][l31] + x2p4[1][l31] + x2p4[2][l31] + x2p4[3][l31];

    f32x16 acc[2];
    acc[0] = (f32x16)0.f;
    acc[1] = (f32x16)0.f;

    // B: 3-slot rotation, distance 2
    bf16x8 bs[3][2];
#pragma unroll
    for (int p = 0; p < 2; ++p)
#pragma unroll
        for (int j2 = 0; j2 < 2; ++j2)
            bs[p][j2] = *(const bf16x8*)(bl + (j2 * 16 + p) * 512);

    // A-frag: 3-slot rotation, distance 2 (LDS)
    bf16x8 af[3];
    af[0] = *(const bf16x8*)&Af[((0 * 2 + hi) * 32 + l31) * 8];
    af[1] = *(const bf16x8*)&Af[((1 * 2 + hi) * 32 + l31) * 8];

#pragma unroll
    for (int ks = 0; ks < 16; ++ks) {
        const int cur = ks % 3;                  // compile-time after unroll

        // issue B(ks+2) and A(ks+2) into the free slot
        if (ks < 14) {
            const int nxt = (ks + 2) % 3;
#pragma unroll
            for (int j2 = 0; j2 < 2; ++j2)
                bs[nxt][j2] = *(const bf16x8*)(bl + (j2 * 16 + ks + 2) * 512);
            af[nxt] = *(const bf16x8*)&Af[(((ks + 2) * 2 + hi) * 32 + l31) * 8];
        }

#pragma unroll
        for (int j2 = 0; j2 < 2; ++j2)
            acc[j2] = __builtin_amdgcn_mfma_f32_32x32x16_bf16(
                af[cur], bs[cur][j2], acc[j2], 0, 0, 0);
    }

    // ---- pass 1: q = rcp(1+d), per-row partial sums -> LDS ----
#pragma unroll
    for (int r = 0; r < 16; ++r) {
        const int rr = (r & 3) + 8 * (r >> 2) + 4 * hi;   // row 0..31
        const float x2r = __shfl(x2l, rr);                // lane rr has row rr
        float s = 0.f;
#pragma unroll
        for (int j2 = 0; j2 < 2; ++j2) {
            float d = x2r + c2v[j2] - 2.f * acc[j2][r];
            float q = frcp(1.f + d);
            acc[j2][r] = q;
            s += q;
        }
        s += __shfl_xor(s, 1);
        s += __shfl_xor(s, 2);
        s += __shfl_xor(s, 4);
        s += __shfl_xor(s, 8);
        s += __shfl_xor(s, 16);
        if (l31 == 0) rowsum[w][rr] = s;
    }
    __syncthreads();

    // ---- pass 2: normalize + full-line stores ----
#pragma unroll
    for (int r = 0; r < 16; ++r) {
        const int rr = (r & 3) + 8 * (r >> 2) + 4 * hi;
        const float inv = frcp(rowsum[0][rr] + rowsum[1][rr] +
                               rowsum[2][rr] + rowsum[3][rr]);
        float* op = out + (row0 + (size_t)rr) * KC + w * 64 + l31;
#pragma unroll
        for (int j2 = 0; j2 < 2; ++j2)
            op[j2 * 32] = acc[j2][r] * inv;   // 2 x 128-B full lines / instr
    }
}

extern "C" void kernel_launch(void* const* d_in, const int* in_sizes, int n_in,
                              void* d_out, int out_size, void* d_ws, size_t ws_size,
                              hipStream_t stream) {
    const float* ctx  = (const float*)d_in[0];
    const float* clus = (const float*)d_in[1];
    float* out = (float*)d_out;

    short* wsb = (short*)d_ws;                               // bf16 fragment image
    float* c2  = (float*)((char*)d_ws + CL_SHORTS * 2);      // 256 fp32 norms

    const int nrows = in_sizes[0] / DD;                      // 524288
    const int grid  = nrows / BM;                            // 16384

    hipLaunchKernelGGL(prep_clusters, dim3(KC), dim3(64), 0, stream, clus, wsb, c2);
    hipLaunchKernelGGL(cluster_q_main, dim3(grid), dim3(256), 0, stream,
                       ctx, wsb, c2, out);
}

// Round 10
// 268.181 us; speedup vs baseline: 1.6548x; 1.0135x over previous
//
#include <hip/hip_runtime.h>
#include <hip/hip_bf16.h>

// clusterLayer: q = rownorm( 1 / (1 + ||x||^2 + ||c||^2 - 2 x.cT) )
// N=524288, K=256, D=256. fp32 in/out.
// Kernel 0: clusters fp32 -> bf16 in 32x32x16-MFMA-fragment order
//   (1 KiB per (nj,ks) fragment) + fp32 c2 norms, in d_ws.
// Main (BM=32, 512 thr = 8 waves = 8 col-eighths, max-occupancy build):
//   - per wave: 32 rows x 32 cols -> acc = 16 regs; total ~55 regs
//     -> launch_bounds(512,8): 8 waves/SIMD, 32 waves/CU (100%).
//   - A converted once per block into 16-KiB LDS (fragment order);
//     each wave stages its 32-float k-slice of all 32 rows.
//   - K-loop: 1 ds_read_b128 (A, 3-slot/d2) + 1 global B-frag (L2-hot,
//     3-slot/d2) + 1 MFMA per step.
//   - VALU diet: v_cvt_pk_bf16_f32, v_rcp_f32; per-lane inv via
//     conflict-free stride-4 LDS reads + shfl (no per-r re-reads).
//   - Full-line stores (2 x 128-B lines per store instr).

#define DD 256
#define KC 256
#define BM 32
#define CL_SHORTS (KC * DD)            // 65536 shorts = 131072 B

typedef __attribute__((ext_vector_type(4)))  float f32x4;
typedef __attribute__((ext_vector_type(16))) float f32x16;
typedef __attribute__((ext_vector_type(8)))  short bf16x8;
typedef __attribute__((ext_vector_type(4)))  short bf16x4;
typedef __attribute__((ext_vector_type(4)))  unsigned u32x4;

__device__ __forceinline__ short f2bf(float f) {
    union { float f; unsigned u; } v; v.f = f;
    unsigned r = (v.u + 0x7fffu + ((v.u >> 16) & 1u)) >> 16;
    return (short)r;
}

// packed fp32->bf16 RNE: dst.lo = cvt(a), dst.hi = cvt(b)
__device__ __forceinline__ unsigned cvtpk(float a, float b) {
    unsigned r;
    asm("v_cvt_pk_bf16_f32 %0, %1, %2" : "=v"(r) : "v"(a), "v"(b));
    return r;
}

__device__ __forceinline__ float frcp(float x) {
    return __builtin_amdgcn_rcpf(x);
}

__device__ __forceinline__ f32x4 ld4(const float* p) { return *(const f32x4*)p; }

// ---------------- Kernel 0: prep clusters (fragment-order bf16 + norms) ----
__global__ __launch_bounds__(64)
void prep_clusters(const float* __restrict__ clus,
                   short* __restrict__ wsb, float* __restrict__ c2) {
    const int c = blockIdx.x;      // cluster row 0..255
    const int t = threadIdx.x;     // 0..63, 4 floats each
    f32x4 v = *(const f32x4*)(clus + c * DD + t * 4);
    bf16x4 o;
    o[0] = f2bf(v[0]); o[1] = f2bf(v[1]); o[2] = f2bf(v[2]); o[3] = f2bf(v[3]);

    // fragment layout: frag(nj,ks) = 512 contiguous shorts; within it,
    // lane (hi*32+l31) holds clusters[nj*32+l31][ks*16+hi*8 .. +8].
    const int j    = t >> 1;       // 8-elem chunk index within row (k/8)
    const int ks   = j >> 1;
    const int hi   = j & 1;
    const int half = t & 1;        // which 4-elem half of the chunk
    const int nj   = c >> 5;
    const int l31  = c & 31;
    *(bf16x4*)&wsb[(((nj * 16 + ks) * 64 + hi * 32 + l31) << 3) + half * 4] = o;

    float s = v[0]*v[0] + v[1]*v[1] + v[2]*v[2] + v[3]*v[3];
    s += __shfl_xor(s, 1);  s += __shfl_xor(s, 2);  s += __shfl_xor(s, 4);
    s += __shfl_xor(s, 8);  s += __shfl_xor(s, 16); s += __shfl_xor(s, 32);
    if (t == 0) c2[c] = s;
}

// ---------------- Main kernel ----------------
__global__ __launch_bounds__(512, 8)
void cluster_q_main(const float* __restrict__ ctx,
                    const short* __restrict__ wsb,
                    const float* __restrict__ c2g,
                    float* __restrict__ out) {
    __shared__ short Af[32 * 32 * 8];    // 16 KiB: [j=k/8][row][8 shorts]
    __shared__ float x2p8[8][BM];        // per-(wave,row) |x|^2 partials
    __shared__ float rowsum[8][BM];      // per-(wave,row) q-sums

    const int t    = threadIdx.x;
    const int lane = t & 63;
    const int w    = t >> 6;             // wave = col-eighth 0..7
    const int l31  = lane & 31;
    const int hi   = lane >> 5;
    const size_t row0 = (size_t)blockIdx.x * BM;

    // ---- stage A: wave w converts k-range [w*32, w*32+32) of all 32 rows ----
    {
        const int r    = lane >> 1;      // row 0..31
        const int half = lane & 1;       // 16-float half of the slice
        const float* src = ctx + (row0 + (size_t)r) * DD + w * 32 + half * 16;
        f32x4 u[4];
#pragma unroll
        for (int i = 0; i < 4; ++i)      // 4 independent loads, all in flight
            u[i] = ld4(src + i * 4);
        float xs = 0.f;
#pragma unroll
        for (int c = 0; c < 2; ++c) {    // two 8-float j-chunks
            f32x4 a0 = u[2*c], a1 = u[2*c+1];
            u32x4 o;
            o[0] = cvtpk(a0[0], a0[1]);
            o[1] = cvtpk(a0[2], a0[3]);
            o[2] = cvtpk(a1[0], a1[1]);
            o[3] = cvtpk(a1[2], a1[3]);
            xs += a0[0]*a0[0] + a0[1]*a0[1] + a0[2]*a0[2] + a0[3]*a0[3]
                + a1[0]*a1[0] + a1[1]*a1[1] + a1[2]*a1[2] + a1[3]*a1[3];
            const int j = w * 4 + half * 2 + c;          // k/8 chunk index
            *(u32x4*)&Af[(j * 32 + r) * 8] = o;
        }
        xs += __shfl_xor(xs, 1);                         // combine halves
        if (half == 0) x2p8[w][r] = xs;
    }

    // B fragment base: this wave's col-tile nj = w, frag (w*16+ks)*512
    const short* bl = wsb + (size_t)(w * 16) * 512 + lane * 8;

    // hoisted c2 load (L2-hot)
    const float c2v = c2g[w * 32 + l31];

    __syncthreads();

    // |x|^2 total for row l31 (stride-4 conflict-free, broadcast across hi)
    float x2l = 0.f;
#pragma unroll
    for (int q = 0; q < 8; ++q) x2l += x2p8[q][l31];

    f32x16 acc = (f32x16)0.f;

    // B: 3-slot rotation, distance 2
    bf16x8 bs[3];
    bs[0] = *(const bf16x8*)(bl + 0 * 512);
    bs[1] = *(const bf16x8*)(bl + 1 * 512);

    // A-frag: 3-slot rotation, distance 2 (LDS)
    bf16x8 af[3];
    af[0] = *(const bf16x8*)&Af[((0 * 2 + hi) * 32 + l31) * 8];
    af[1] = *(const bf16x8*)&Af[((1 * 2 + hi) * 32 + l31) * 8];

#pragma unroll
    for (int ks = 0; ks < 16; ++ks) {
        const int cur = ks % 3;                  // compile-time after unroll

        // issue B(ks+2) and A(ks+2) into the free slot
        if (ks < 14) {
            const int nxt = (ks + 2) % 3;
            bs[nxt] = *(const bf16x8*)(bl + (ks + 2) * 512);
            af[nxt] = *(const bf16x8*)&Af[(((ks + 2) * 2 + hi) * 32 + l31) * 8];
        }

        acc = __builtin_amdgcn_mfma_f32_32x32x16_bf16(af[cur], bs[cur], acc, 0, 0, 0);
    }

    // ---- pass 1: q = rcp(1+d), per-row partial sums -> LDS ----
#pragma unroll
    for (int r = 0; r < 16; ++r) {
        const int rr = (r & 3) + 8 * (r >> 2) + 4 * hi;   // row 0..31
        const float x2r = __shfl(x2l, rr);                // lane rr has row rr
        const float d = x2r + c2v - 2.f * acc[r];
        float s = frcp(1.f + d);
        acc[r] = s;
        s += __shfl_xor(s, 1);
        s += __shfl_xor(s, 2);
        s += __shfl_xor(s, 4);
        s += __shfl_xor(s, 8);
        s += __shfl_xor(s, 16);
        if (l31 == 0) rowsum[w][rr] = s;
    }
    __syncthreads();

    // ---- pass 2: per-lane row inverse (stride-4 conflict-free reads),
    //      then normalize + full-line stores ----
    float sl = 0.f;
#pragma unroll
    for (int q = 0; q < 8; ++q) sl += rowsum[q][l31];
    const float invl = frcp(sl);                          // inv for row l31

#pragma unroll
    for (int r = 0; r < 16; ++r) {
        const int rr = (r & 3) + 8 * (r >> 2) + 4 * hi;
        const float inv = __shfl(invl, rr);
        float* op = out + (row0 + (size_t)rr) * KC + w * 32 + l31;
        op[0] = acc[r] * inv;     // 2 x 128-B full lines per store instr
    }
}

extern "C" void kernel_launch(void* const* d_in, const int* in_sizes, int n_in,
                              void* d_out, int out_size, void* d_ws, size_t ws_size,
                              hipStream_t stream) {
    const float* ctx  = (const float*)d_in[0];
    const float* clus = (const float*)d_in[1];
    float* out = (float*)d_out;

    short* wsb = (short*)d_ws;                               // bf16 fragment image
    float* c2  = (float*)((char*)d_ws + CL_SHORTS * 2);      // 256 fp32 norms

    const int nrows = in_sizes[0] / DD;                      // 524288
    const int grid  = nrows / BM;                            // 16384

    hipLaunchKernelGGL(prep_clusters, dim3(KC), dim3(64), 0, stream, clus, wsb, c2);
    hipLaunchKernelGGL(cluster_q_main, dim3(grid), dim3(512), 0, stream,
                       ctx, wsb, c2, out);
}

// Round 11
// 252.665 us; speedup vs baseline: 1.7564x; 1.0614x over previous
//
#include <hip/hip_runtime.h>
#include <hip/hip_bf16.h>

// clusterLayer: q = rownorm( 1 / (1 + ||x||^2 + ||c||^2 - 2 x.cT) )
// N=524288, K=256, D=256. fp32 in/out.
// Kernel 0: clusters fp32 -> bf16 in 32x32x16-MFMA-fragment order
//   (1 KiB per (nj,ks) fragment) + fp32 c2 norms, in d_ws.
// Main (BM=32, 512 thr = 8 waves = 8 col-eighths, 8 waves/SIMD):
//   - per wave: 32 rows x 32 cols -> acc = 16 regs.
//   - A converted once per block into 16-KiB LDS (fragment order).
//   - K-loop: 1 ds_read_b128 (A) + 1 global B-frag (L2-hot) + 1 MFMA,
//     both 3-slot/d2 rotations.
//   - Epilogue reductions on the VALU pipe, NOT the LDS pipe (r10 fix):
//     DPP row_shr/bcast adds for 32-lane row sums, v_readlane pairs for
//     per-row broadcasts. DS ops/wave: 165 -> ~53.
//   - Full-line stores (2 x 128-B lines per store instr).

#define DD 256
#define KC 256
#define BM 32
#define CL_SHORTS (KC * DD)            // 65536 shorts = 131072 B

typedef __attribute__((ext_vector_type(4)))  float f32x4;
typedef __attribute__((ext_vector_type(16))) float f32x16;
typedef __attribute__((ext_vector_type(8)))  short bf16x8;
typedef __attribute__((ext_vector_type(4)))  short bf16x4;
typedef __attribute__((ext_vector_type(4)))  unsigned u32x4;

__device__ __forceinline__ short f2bf(float f) {
    union { float f; unsigned u; } v; v.f = f;
    unsigned r = (v.u + 0x7fffu + ((v.u >> 16) & 1u)) >> 16;
    return (short)r;
}

// packed fp32->bf16 RNE: dst.lo = cvt(a), dst.hi = cvt(b)
__device__ __forceinline__ unsigned cvtpk(float a, float b) {
    unsigned r;
    asm("v_cvt_pk_bf16_f32 %0, %1, %2" : "=v"(r) : "v"(a), "v"(b));
    return r;
}

__device__ __forceinline__ float frcp(float x) {
    return __builtin_amdgcn_rcpf(x);
}

// v += dpp_move(v, CTRL); invalid lanes contribute 0 (old=0, bound_ctrl off).
// VALU pipe: replaces ds_swizzle-based __shfl_xor.
template<int CTRL>
__device__ __forceinline__ float dpp_add(float v) {
    int iv = __builtin_bit_cast(int, v);
    int mv = __builtin_amdgcn_update_dpp(0, iv, CTRL, 0xf, 0xf, false);
    return v + __builtin_bit_cast(float, mv);
}
#define ROW_SHR1   0x111
#define ROW_SHR2   0x112
#define ROW_SHR4   0x114
#define ROW_SHR8   0x118
#define ROW_BC15   0x142
#define QUAD_SWAP1 0xB1    // quad_perm [1,0,3,2]

__device__ __forceinline__ float readlane_f(float v, int l) {
    return __builtin_bit_cast(float,
        __builtin_amdgcn_readlane(__builtin_bit_cast(int, v), l));
}

__device__ __forceinline__ f32x4 ld4(const float* p) { return *(const f32x4*)p; }

// ---------------- Kernel 0: prep clusters (fragment-order bf16 + norms) ----
__global__ __launch_bounds__(64)
void prep_clusters(const float* __restrict__ clus,
                   short* __restrict__ wsb, float* __restrict__ c2) {
    const int c = blockIdx.x;      // cluster row 0..255
    const int t = threadIdx.x;     // 0..63, 4 floats each
    f32x4 v = *(const f32x4*)(clus + c * DD + t * 4);
    bf16x4 o;
    o[0] = f2bf(v[0]); o[1] = f2bf(v[1]); o[2] = f2bf(v[2]); o[3] = f2bf(v[3]);

    // fragment layout: frag(nj,ks) = 512 contiguous shorts; within it,
    // lane (hi*32+l31) holds clusters[nj*32+l31][ks*16+hi*8 .. +8].
    const int j    = t >> 1;       // 8-elem chunk index within row (k/8)
    const int ks   = j >> 1;
    const int hi   = j & 1;
    const int half = t & 1;        // which 4-elem half of the chunk
    const int nj   = c >> 5;
    const int l31  = c & 31;
    *(bf16x4*)&wsb[(((nj * 16 + ks) * 64 + hi * 32 + l31) << 3) + half * 4] = o;

    float s = v[0]*v[0] + v[1]*v[1] + v[2]*v[2] + v[3]*v[3];
    s += __shfl_xor(s, 1);  s += __shfl_xor(s, 2);  s += __shfl_xor(s, 4);
    s += __shfl_xor(s, 8);  s += __shfl_xor(s, 16); s += __shfl_xor(s, 32);
    if (t == 0) c2[c] = s;
}

// ---------------- Main kernel ----------------
__global__ __launch_bounds__(512, 8)
void cluster_q_main(const float* __restrict__ ctx,
                    const short* __restrict__ wsb,
                    const float* __restrict__ c2g,
                    float* __restrict__ out) {
    __shared__ short Af[32 * 32 * 8];    // 16 KiB: [j=k/8][row][8 shorts]
    __shared__ float x2p8[8][BM];        // per-(wave,row) |x|^2 partials
    __shared__ float rowsum[8][BM];      // per-(wave,row) q-sums

    const int t    = threadIdx.x;
    const int lane = t & 63;
    const int w    = t >> 6;             // wave = col-eighth 0..7
    const int l31  = lane & 31;
    const int hi   = lane >> 5;
    const size_t row0 = (size_t)blockIdx.x * BM;

    // ---- stage A: wave w converts k-range [w*32, w*32+32) of all 32 rows ----
    {
        const int r    = lane >> 1;      // row 0..31
        const int half = lane & 1;       // 16-float half of the slice
        const float* src = ctx + (row0 + (size_t)r) * DD + w * 32 + half * 16;
        f32x4 u[4];
#pragma unroll
        for (int i = 0; i < 4; ++i)      // 4 independent loads, all in flight
            u[i] = ld4(src + i * 4);
        float xs = 0.f;
#pragma unroll
        for (int c = 0; c < 2; ++c) {    // two 8-float j-chunks
            f32x4 a0 = u[2*c], a1 = u[2*c+1];
            u32x4 o;
            o[0] = cvtpk(a0[0], a0[1]);
            o[1] = cvtpk(a0[2], a0[3]);
            o[2] = cvtpk(a1[0], a1[1]);
            o[3] = cvtpk(a1[2], a1[3]);
            xs += a0[0]*a0[0] + a0[1]*a0[1] + a0[2]*a0[2] + a0[3]*a0[3]
                + a1[0]*a1[0] + a1[1]*a1[1] + a1[2]*a1[2] + a1[3]*a1[3];
            const int j = w * 4 + half * 2 + c;          // k/8 chunk index
            *(u32x4*)&Af[(j * 32 + r) * 8] = o;
        }
        xs = dpp_add<QUAD_SWAP1>(xs);                    // combine halves (VALU)
        if (half == 0) x2p8[w][r] = xs;
    }

    // B fragment base: this wave's col-tile nj = w, frag (w*16+ks)*512
    const short* bl = wsb + (size_t)(w * 16) * 512 + lane * 8;

    // hoisted c2 load (L2-hot)
    const float c2v = c2g[w * 32 + l31];

    __syncthreads();

    // |x|^2 total for row l31 (stride-4 conflict-free, broadcast across hi)
    float x2l = 0.f;
#pragma unroll
    for (int q = 0; q < 8; ++q) x2l += x2p8[q][l31];

    f32x16 acc = (f32x16)0.f;

    // B: 3-slot rotation, distance 2
    bf16x8 bs[3];
    bs[0] = *(const bf16x8*)(bl + 0 * 512);
    bs[1] = *(const bf16x8*)(bl + 1 * 512);

    // A-frag: 3-slot rotation, distance 2 (LDS)
    bf16x8 af[3];
    af[0] = *(const bf16x8*)&Af[((0 * 2 + hi) * 32 + l31) * 8];
    af[1] = *(const bf16x8*)&Af[((1 * 2 + hi) * 32 + l31) * 8];

#pragma unroll
    for (int ks = 0; ks < 16; ++ks) {
        const int cur = ks % 3;                  // compile-time after unroll

        // issue B(ks+2) and A(ks+2) into the free slot
        if (ks < 14) {
            const int nxt = (ks + 2) % 3;
            bs[nxt] = *(const bf16x8*)(bl + (ks + 2) * 512);
            af[nxt] = *(const bf16x8*)&Af[(((ks + 2) * 2 + hi) * 32 + l31) * 8];
        }

        acc = __builtin_amdgcn_mfma_f32_32x32x16_bf16(af[cur], bs[cur], acc, 0, 0, 0);
    }

    // ---- pass 1: q = rcp(1+d), per-row sums via DPP (VALU pipe) ----
#pragma unroll
    for (int r = 0; r < 16; ++r) {
        const int rr0 = (r & 3) + 8 * (r >> 2);           // hi=0 row; hi=1: +4
        const float xa = readlane_f(x2l, rr0);            // row rr0 |x|^2
        const float xb = readlane_f(x2l, rr0 + 4);        // row rr0+4 |x|^2
        const float x2r = hi ? xb : xa;
        const float d = x2r + c2v - 2.f * acc[r];
        float s = frcp(1.f + d);
        acc[r] = s;
        // 32-lane half-sums: lane31 = sum(l 0..31), lane63 = sum(l 32..63)
        s = dpp_add<ROW_SHR1>(s);
        s = dpp_add<ROW_SHR2>(s);
        s = dpp_add<ROW_SHR4>(s);
        s = dpp_add<ROW_SHR8>(s);
        s = dpp_add<ROW_BC15>(s);
        if (l31 == 31) rowsum[w][rr0 + 4 * hi] = s;
    }
    __syncthreads();

    // ---- pass 2: per-lane row inverse, normalize + full-line stores ----
    float sl = 0.f;
#pragma unroll
    for (int q = 0; q < 8; ++q) sl += rowsum[q][l31];
    const float invl = frcp(sl);                          // inv for row l31

#pragma unroll
    for (int r = 0; r < 16; ++r) {
        const int rr0 = (r & 3) + 8 * (r >> 2);
        const float ia = readlane_f(invl, rr0);
        const float ib = readlane_f(invl, rr0 + 4);
        const float inv = hi ? ib : ia;
        float* op = out + (row0 + (size_t)(rr0 + 4 * hi)) * KC + w * 32 + l31;
        op[0] = acc[r] * inv;     // 2 x 128-B full lines per store instr
    }
}

extern "C" void kernel_launch(void* const* d_in, const int* in_sizes, int n_in,
                              void* d_out, int out_size, void* d_ws, size_t ws_size,
                              hipStream_t stream) {
    const float* ctx  = (const float*)d_in[0];
    const float* clus = (const float*)d_in[1];
    float* out = (float*)d_out;

    short* wsb = (short*)d_ws;                               // bf16 fragment image
    float* c2  = (float*)((char*)d_ws + CL_SHORTS * 2);      // 256 fp32 norms

    const int nrows = in_sizes[0] / DD;                      // 524288
    const int grid  = nrows / BM;                            // 16384

    hipLaunchKernelGGL(prep_clusters, dim3(KC), dim3(64), 0, stream, clus, wsb, c2);
    hipLaunchKernelGGL(cluster_q_main, dim3(grid), dim3(512), 0, stream,
                       ctx, wsb, c2, out);
}

// Round 12
// 246.827 us; speedup vs baseline: 1.7979x; 1.0237x over previous
//
#include <hip/hip_runtime.h>
#include <hip/hip_bf16.h>

// clusterLayer: q = rownorm( 1 / (1 + ||x||^2 + ||c||^2 - 2 x.cT) )
// N=524288, K=256, D=256. fp32 in/out.
// Kernel 0: clusters fp32 -> bf16 in 32x32x16-MFMA-fragment order
//   (1 KiB per (nj,ks) fragment) + fp32 c2 norms, in d_ws.
// Main (BM=64, 512 thr = 8 waves = 8 col-eighths x TWO M-tiles each):
//   - per wave: 64 rows x 32 cols -> acc[2] (32 regs); 2 MFMA per K-step
//     SHARE one B-fragment -> B L2 traffic halves vs BM=32 (2.1->1.05 GB).
//   - A converted once per block into 32-KiB LDS (fragment order).
//   - K-loop: 2 ds_read_b128 (A ping-pong) + 1 global B-frag (L2-hot,
//     3-slot/d2) + 2 MFMA per step.
//   - Epilogue reductions on the VALU pipe (DPP row_shr/bcast + readlane).
//   - launch_bounds(512,6): reg cap 85, 6 waves/SIMD, 3 blocks/CU (LDS 110K).

#define DD 256
#define KC 256
#define BM 64
#define CL_SHORTS (KC * DD)            // 65536 shorts = 131072 B

typedef __attribute__((ext_vector_type(4)))  float f32x4;
typedef __attribute__((ext_vector_type(16))) float f32x16;
typedef __attribute__((ext_vector_type(8)))  short bf16x8;
typedef __attribute__((ext_vector_type(4)))  short bf16x4;
typedef __attribute__((ext_vector_type(4)))  unsigned u32x4;

__device__ __forceinline__ short f2bf(float f) {
    union { float f; unsigned u; } v; v.f = f;
    unsigned r = (v.u + 0x7fffu + ((v.u >> 16) & 1u)) >> 16;
    return (short)r;
}

// packed fp32->bf16 RNE: dst.lo = cvt(a), dst.hi = cvt(b)
__device__ __forceinline__ unsigned cvtpk(float a, float b) {
    unsigned r;
    asm("v_cvt_pk_bf16_f32 %0, %1, %2" : "=v"(r) : "v"(a), "v"(b));
    return r;
}

__device__ __forceinline__ float frcp(float x) {
    return __builtin_amdgcn_rcpf(x);
}

// v += dpp_move(v, CTRL); VALU pipe (replaces ds_swizzle-based __shfl_xor).
template<int CTRL>
__device__ __forceinline__ float dpp_add(float v) {
    int iv = __builtin_bit_cast(int, v);
    int mv = __builtin_amdgcn_update_dpp(0, iv, CTRL, 0xf, 0xf, false);
    return v + __builtin_bit_cast(float, mv);
}
#define ROW_SHR1   0x111
#define ROW_SHR2   0x112
#define ROW_SHR4   0x114
#define ROW_SHR8   0x118
#define ROW_BC15   0x142
#define QUAD_SWAP1 0xB1    // quad_perm [1,0,3,2]

__device__ __forceinline__ float readlane_f(float v, int l) {
    return __builtin_bit_cast(float,
        __builtin_amdgcn_readlane(__builtin_bit_cast(int, v), l));
}

__device__ __forceinline__ f32x4 ld4(const float* p) { return *(const f32x4*)p; }

// ---------------- Kernel 0: prep clusters (fragment-order bf16 + norms) ----
__global__ __launch_bounds__(64)
void prep_clusters(const float* __restrict__ clus,
                   short* __restrict__ wsb, float* __restrict__ c2) {
    const int c = blockIdx.x;      // cluster row 0..255
    const int t = threadIdx.x;     // 0..63, 4 floats each
    f32x4 v = *(const f32x4*)(clus + c * DD + t * 4);
    bf16x4 o;
    o[0] = f2bf(v[0]); o[1] = f2bf(v[1]); o[2] = f2bf(v[2]); o[3] = f2bf(v[3]);

    // fragment layout: frag(nj,ks) = 512 contiguous shorts; within it,
    // lane (hi*32+l31) holds clusters[nj*32+l31][ks*16+hi*8 .. +8].
    const int j    = t >> 1;       // 8-elem chunk index within row (k/8)
    const int ks   = j >> 1;
    const int hi   = j & 1;
    const int half = t & 1;        // which 4-elem half of the chunk
    const int nj   = c >> 5;
    const int l31  = c & 31;
    *(bf16x4*)&wsb[(((nj * 16 + ks) * 64 + hi * 32 + l31) << 3) + half * 4] = o;

    float s = v[0]*v[0] + v[1]*v[1] + v[2]*v[2] + v[3]*v[3];
    s += __shfl_xor(s, 1);  s += __shfl_xor(s, 2);  s += __shfl_xor(s, 4);
    s += __shfl_xor(s, 8);  s += __shfl_xor(s, 16); s += __shfl_xor(s, 32);
    if (t == 0) c2[c] = s;
}

// ---------------- Main kernel ----------------
__global__ __launch_bounds__(512, 6)
void cluster_q_main(const float* __restrict__ ctx,
                    const short* __restrict__ wsb,
                    const float* __restrict__ c2g,
                    float* __restrict__ out) {
    __shared__ short Af[32 * 64 * 8];    // 32 KiB: [j=k/8][row 0..63][8 shorts]
    __shared__ float x2p8[8][BM];        // per-(wave,row) |x|^2 partials
    __shared__ float rowsum[8][BM];      // per-(wave,row) q-sums

    const int t    = threadIdx.x;
    const int lane = t & 63;
    const int w    = t >> 6;             // wave = col-eighth 0..7
    const int l31  = lane & 31;
    const int hi   = lane >> 5;
    const size_t row0 = (size_t)blockIdx.x * BM;

    // ---- stage A: wave w converts k-slice [w*32, w*32+32) of all 64 rows ----
    {
        const int r0   = lane >> 1;      // row 0..31 (and +32)
        const int half = lane & 1;       // 16-float half of the slice
        f32x4 u[8];
#pragma unroll
        for (int m = 0; m < 2; ++m) {    // 8 independent loads, all in flight
            const float* src = ctx + (row0 + (size_t)(m * 32 + r0)) * DD
                             + w * 32 + half * 16;
#pragma unroll
            for (int i = 0; i < 4; ++i)
                u[m * 4 + i] = ld4(src + i * 4);
        }
#pragma unroll
        for (int m = 0; m < 2; ++m) {
            float xs = 0.f;
#pragma unroll
            for (int c = 0; c < 2; ++c) {    // two 8-float j-chunks
                f32x4 a0 = u[m * 4 + 2 * c], a1 = u[m * 4 + 2 * c + 1];
                u32x4 o;
                o[0] = cvtpk(a0[0], a0[1]);
                o[1] = cvtpk(a0[2], a0[3]);
                o[2] = cvtpk(a1[0], a1[1]);
                o[3] = cvtpk(a1[2], a1[3]);
                xs += a0[0]*a0[0] + a0[1]*a0[1] + a0[2]*a0[2] + a0[3]*a0[3]
                    + a1[0]*a1[0] + a1[1]*a1[1] + a1[2]*a1[2] + a1[3]*a1[3];
                const int j = w * 4 + half * 2 + c;      // k/8 chunk index
                *(u32x4*)&Af[(j * 64 + m * 32 + r0) * 8] = o;
            }
            xs = dpp_add<QUAD_SWAP1>(xs);                // combine halves (VALU)
            if (half == 0) x2p8[w][m * 32 + r0] = xs;
        }
    }

    // B fragment base: this wave's col-tile nj = w, frag (w*16+ks)*512
    const short* bl = wsb + (size_t)(w * 16) * 512 + lane * 8;

    // hoisted c2 load (L2-hot)
    const float c2v = c2g[w * 32 + l31];

    __syncthreads();

    // |x|^2 totals: lane l31 accumulates rows l31 and 32+l31
    float x2A = 0.f, x2B = 0.f;
#pragma unroll
    for (int q = 0; q < 8; ++q) {
        x2A += x2p8[q][l31];
        x2B += x2p8[q][32 + l31];
    }

    f32x16 acc0 = (f32x16)0.f, acc1 = (f32x16)0.f;

    // B: 3-slot rotation, distance 2 (L2 latency cover)
    bf16x8 bs[3];
    bs[0] = *(const bf16x8*)(bl + 0 * 512);
    bs[1] = *(const bf16x8*)(bl + 1 * 512);

    // A-frags: ping-pong, distance 1 (LDS is fast)
    bf16x8 afA0 = *(const bf16x8*)&Af[((0 + hi) * 64 +  0 + l31) * 8];
    bf16x8 afA1 = *(const bf16x8*)&Af[((0 + hi) * 64 + 32 + l31) * 8];
    bf16x8 afB0, afB1;

#pragma unroll
    for (int ks = 0; ks < 16; ++ks) {
        const int cur = ks % 3;                  // compile-time after unroll
        const bool even = (ks & 1) == 0;

        // issue B(ks+2) into the free slot
        if (ks < 14) {
            const int nxt = (ks + 2) % 3;
            bs[nxt] = *(const bf16x8*)(bl + (ks + 2) * 512);
        }
        // issue A-frags for ks+1 into the other bank
        if (ks < 15) {
            const int jn = (ks + 1) * 2 + hi;
            bf16x8 v0 = *(const bf16x8*)&Af[(jn * 64 +  0 + l31) * 8];
            bf16x8 v1 = *(const bf16x8*)&Af[(jn * 64 + 32 + l31) * 8];
            if (even) { afB0 = v0; afB1 = v1; }
            else      { afA0 = v0; afA1 = v1; }
        }

        const bf16x8 a0 = even ? afA0 : afB0;
        const bf16x8 a1 = even ? afA1 : afB1;
        acc0 = __builtin_amdgcn_mfma_f32_32x32x16_bf16(a0, bs[cur], acc0, 0, 0, 0);
        acc1 = __builtin_amdgcn_mfma_f32_32x32x16_bf16(a1, bs[cur], acc1, 0, 0, 0);
    }

    // ---- pass 1: q = rcp(1+d), per-row sums via DPP (VALU pipe) ----
#pragma unroll
    for (int r = 0; r < 16; ++r) {
        const int rr0 = (r & 3) + 8 * (r >> 2);           // hi=0 row; hi=1: +4
        // M-tile 0 (rows rr0 / rr0+4)
        {
            const float xa = readlane_f(x2A, rr0);
            const float xb = readlane_f(x2A, rr0 + 4);
            const float x2r = hi ? xb : xa;
            const float d = x2r + c2v - 2.f * acc0[r];
            float s = frcp(1.f + d);
            acc0[r] = s;
            s = dpp_add<ROW_SHR1>(s);
            s = dpp_add<ROW_SHR2>(s);
            s = dpp_add<ROW_SHR4>(s);
            s = dpp_add<ROW_SHR8>(s);
            s = dpp_add<ROW_BC15>(s);
            if (l31 == 31) rowsum[w][rr0 + 4 * hi] = s;
        }
        // M-tile 1 (rows 32+rr0 / 32+rr0+4)
        {
            const float xa = readlane_f(x2B, rr0);
            const float xb = readlane_f(x2B, rr0 + 4);
            const float x2r = hi ? xb : xa;
            const float d = x2r + c2v - 2.f * acc1[r];
            float s = frcp(1.f + d);
            acc1[r] = s;
            s = dpp_add<ROW_SHR1>(s);
            s = dpp_add<ROW_SHR2>(s);
            s = dpp_add<ROW_SHR4>(s);
            s = dpp_add<ROW_SHR8>(s);
            s = dpp_add<ROW_BC15>(s);
            if (l31 == 31) rowsum[w][32 + rr0 + 4 * hi] = s;
        }
    }
    __syncthreads();

    // ---- pass 2: per-lane row inverses, normalize + full-line stores ----
    float slA = 0.f, slB = 0.f;
#pragma unroll
    for (int q = 0; q < 8; ++q) {
        slA += rowsum[q][l31];
        slB += rowsum[q][32 + l31];
    }
    const float invA = frcp(slA);                         // row l31
    const float invB = frcp(slB);                         // row 32+l31

#pragma unroll
    for (int r = 0; r < 16; ++r) {
        const int rr0 = (r & 3) + 8 * (r >> 2);
        {
            const float ia = readlane_f(invA, rr0);
            const float ib = readlane_f(invA, rr0 + 4);
            const float inv = hi ? ib : ia;
            float* op = out + (row0 + (size_t)(rr0 + 4 * hi)) * KC + w * 32 + l31;
            op[0] = acc0[r] * inv;    // 2 x 128-B full lines per store instr
        }
        {
            const float ia = readlane_f(invB, rr0);
            const float ib = readlane_f(invB, rr0 + 4);
            const float inv = hi ? ib : ia;
            float* op = out + (row0 + (size_t)(32 + rr0 + 4 * hi)) * KC + w * 32 + l31;
            op[0] = acc1[r] * inv;
        }
    }
}

extern "C" void kernel_launch(void* const* d_in, const int* in_sizes, int n_in,
                              void* d_out, int out_size, void* d_ws, size_t ws_size,
                              hipStream_t stream) {
    const float* ctx  = (const float*)d_in[0];
    const float* clus = (const float*)d_in[1];
    float* out = (float*)d_out;

    short* wsb = (short*)d_ws;                               // bf16 fragment image
    float* c2  = (float*)((char*)d_ws + CL_SHORTS * 2);      // 256 fp32 norms

    const int nrows = in_sizes[0] / DD;                      // 524288
    const int grid  = nrows / BM;                            // 8192

    hipLaunchKernelGGL(prep_clusters, dim3(KC), dim3(64), 0, stream, clus, wsb, c2);
    hipLaunchKernelGGL(cluster_q_main, dim3(grid), dim3(512), 0, stream,
                       ctx, wsb, c2, out);
}

// Round 13
// 244.015 us; speedup vs baseline: 1.8186x; 1.0115x over previous
//
#include <hip/hip_runtime.h>
#include <hip/hip_bf16.h>

// clusterLayer: q = rownorm( 1 / (1 + ||x||^2 + ||c||^2 - 2 x.cT) )
// N=524288, K=256, D=256. fp32 in/out.
// r13: SWAPPED-operand MFMA + K-augmentation.
//   - Clusters stored as -2*bf16(c) in fragment order, 17 frags/nj:
//     frags 0..15 = K 0..255, frag 16 = aug [1,1,1, limbs3(1+|c|^2), 0,0].
//   - Context staged to LDS (frag order) + aug rows [limbs3(|x|^2),1,1,1]
//     written by wave 0 from x2 partials.
//   - mfma(cluster_frag, context_frag): C lane = context row, reg = cluster.
//     After 17 K-steps acc = 1 + d. q = rcp(acc): no d-math, no c2/x2
//     plumbing, no DPP tree (row sum is IN-LANE), stores are dwordx4
//     directly from acc (4-reg groups = 4 consecutive output columns).
//   - BM=64, 512 thr = 8 waves = 8 col-eighths x 2 M-tiles; 3 barriers.

#define DD 256
#define KC 256
#define BM 64

typedef __attribute__((ext_vector_type(4)))  float f32x4;
typedef __attribute__((ext_vector_type(16))) float f32x16;
typedef __attribute__((ext_vector_type(8)))  short bf16x8;
typedef __attribute__((ext_vector_type(4)))  short bf16x4;
typedef __attribute__((ext_vector_type(4)))  unsigned u32x4;

__device__ __forceinline__ short f2bf(float f) {
    union { float f; unsigned u; } v; v.f = f;
    unsigned r = (v.u + 0x7fffu + ((v.u >> 16) & 1u)) >> 16;
    return (short)r;
}

__device__ __forceinline__ float bf2f(short h) {
    return __builtin_bit_cast(float, ((unsigned)(unsigned short)h) << 16);
}

// packed fp32->bf16 RNE: dst.lo = cvt(a), dst.hi = cvt(b)
__device__ __forceinline__ unsigned cvtpk(float a, float b) {
    unsigned r;
    asm("v_cvt_pk_bf16_f32 %0, %1, %2" : "=v"(r) : "v"(a), "v"(b));
    return r;
}

__device__ __forceinline__ float frcp(float x) {
    return __builtin_amdgcn_rcpf(x);
}

// v += dpp_move(v, CTRL); VALU pipe.
template<int CTRL>
__device__ __forceinline__ float dpp_add(float v) {
    int iv = __builtin_bit_cast(int, v);
    int mv = __builtin_amdgcn_update_dpp(0, iv, CTRL, 0xf, 0xf, false);
    return v + __builtin_bit_cast(float, mv);
}
#define QUAD_SWAP1 0xB1    // quad_perm [1,0,3,2]

__device__ __forceinline__ f32x4 ld4(const float* p) { return *(const f32x4*)p; }

// ---------------- Kernel 0: prep clusters ----------------
// Stores -2*bf16(c) main frags (idx nj*17+ks) + aug frag (nj*17+16):
// hi=0 lane slots = [1,1,1, c2h,c2m,c2l, 0,0] with (c2*) = limbs3(1+|c|^2).
__global__ __launch_bounds__(64)
void prep_clusters(const float* __restrict__ clus, short* __restrict__ wsb) {
    const int c = blockIdx.x;      // cluster row 0..255
    const int t = threadIdx.x;     // 0..63, 4 floats each
    f32x4 v = *(const f32x4*)(clus + c * DD + t * 4);
    bf16x4 o;
    o[0] = f2bf(-2.f * v[0]); o[1] = f2bf(-2.f * v[1]);
    o[2] = f2bf(-2.f * v[2]); o[3] = f2bf(-2.f * v[3]);

    const int j    = t >> 1;       // 8-elem chunk index within row (k/8)
    const int ks   = j >> 1;
    const int hi   = j & 1;
    const int half = t & 1;
    const int nj   = c >> 5;
    const int l31  = c & 31;
    *(bf16x4*)&wsb[(((nj * 17 + ks) * 64 + hi * 32 + l31) << 3) + half * 4] = o;

    float s = v[0]*v[0] + v[1]*v[1] + v[2]*v[2] + v[3]*v[3];   // raw |c|^2
    s += __shfl_xor(s, 1);  s += __shfl_xor(s, 2);  s += __shfl_xor(s, 4);
    s += __shfl_xor(s, 8);  s += __shfl_xor(s, 16); s += __shfl_xor(s, 32);
    if (t == 0) {
        float e = 1.f + s;
        short h = f2bf(e);  float e1 = e - bf2f(h);
        short m = f2bf(e1); float e2 = e1 - bf2f(m);
        short l = f2bf(e2);
        const unsigned one = 0x3F80u;
        u32x4 a;
        a[0] = one | (one << 16);
        a[1] = one | ((unsigned)(unsigned short)h << 16);
        a[2] = (unsigned)(unsigned short)m | ((unsigned)(unsigned short)l << 16);
        a[3] = 0u;
        *(u32x4*)&wsb[((nj * 17 + 16) * 64 + l31) * 8] = a;         // hi=0 slots
        u32x4 z = {0u, 0u, 0u, 0u};
        *(u32x4*)&wsb[((nj * 17 + 16) * 64 + 32 + l31) * 8] = z;    // hi=1 slots
    }
}

// ---------------- Main kernel ----------------
__global__ __launch_bounds__(512, 6)
void cluster_q_main(const float* __restrict__ ctx,
                    const short* __restrict__ wsb,
                    float* __restrict__ out) {
    __shared__ short Af[34 * 64 * 8];    // 34 KiB: j=0..31 main, 32..33 aug
    __shared__ float x2p8[8][64];        // per-(wave,row) |x|^2 partials
    __shared__ float rowsum2[8][2][64];  // per-(wave,hi,row) q half-sums

    const int t    = threadIdx.x;
    const int lane = t & 63;
    const int w    = t >> 6;             // wave = col-eighth 0..7
    const int l31  = lane & 31;
    const int hi   = lane >> 5;
    const size_t row0 = (size_t)blockIdx.x * BM;

    // ---- stage A: wave w converts k-slice [w*32, w*32+32) of all 64 rows ----
    {
        const int r0   = lane >> 1;      // row 0..31 (and +32)
        const int half = lane & 1;       // 16-float half of the slice
        f32x4 u[8];
#pragma unroll
        for (int m = 0; m < 2; ++m) {
            const float* src = ctx + (row0 + (size_t)(m * 32 + r0)) * DD
                             + w * 32 + half * 16;
#pragma unroll
            for (int i = 0; i < 4; ++i)
                u[m * 4 + i] = ld4(src + i * 4);
        }
#pragma unroll
        for (int m = 0; m < 2; ++m) {
            float xs = 0.f;
#pragma unroll
            for (int c = 0; c < 2; ++c) {
                f32x4 a0 = u[m * 4 + 2 * c], a1 = u[m * 4 + 2 * c + 1];
                u32x4 o;
                o[0] = cvtpk(a0[0], a0[1]);
                o[1] = cvtpk(a0[2], a0[3]);
                o[2] = cvtpk(a1[0], a1[1]);
                o[3] = cvtpk(a1[2], a1[3]);
                xs += a0[0]*a0[0] + a0[1]*a0[1] + a0[2]*a0[2] + a0[3]*a0[3]
                    + a1[0]*a1[0] + a1[1]*a1[1] + a1[2]*a1[2] + a1[3]*a1[3];
                const int j = w * 4 + half * 2 + c;      // k/8 chunk index
                *(u32x4*)&Af[(j * 64 + m * 32 + r0) * 8] = o;
            }
            xs = dpp_add<QUAD_SWAP1>(xs);                // combine halves
            if (half == 0) x2p8[w][m * 32 + r0] = xs;
        }
    }

    // cluster fragment base: this wave's col-tile nj = w (17 frags)
    const short* bl = wsb + (size_t)(w * 17) * 512 + lane * 8;

    __syncthreads();   // B1: Af main + x2p8 ready

    // ---- wave 0 writes the context aug rows: [x2h,x2m,x2l,1,1,1,0,0] ----
    if (w == 0) {
        float e = 0.f;
#pragma unroll
        for (int q = 0; q < 8; ++q) e += x2p8[q][lane];
        short h = f2bf(e);  float e1 = e - bf2f(h);
        short m = f2bf(e1); float e2 = e1 - bf2f(m);
        short l = f2bf(e2);
        const unsigned one = 0x3F80u;
        u32x4 o;
        o[0] = (unsigned)(unsigned short)h | ((unsigned)(unsigned short)m << 16);
        o[1] = (unsigned)(unsigned short)l | (one << 16);
        o[2] = one | (one << 16);
        o[3] = 0u;
        *(u32x4*)&Af[(32 * 64 + lane) * 8] = o;          // hi=0 slots
        u32x4 z = {0u, 0u, 0u, 0u};
        *(u32x4*)&Af[(33 * 64 + lane) * 8] = z;          // hi=1 slots
    }

    f32x16 acc0 = (f32x16)0.f, acc1 = (f32x16)0.f;

    // clusters: 3-slot rotation, distance 2 (L2 latency cover)
    bf16x8 bs[3];
    bs[0] = *(const bf16x8*)(bl + 0 * 512);
    bs[1] = *(const bf16x8*)(bl + 1 * 512);

    // context frags: ping-pong from LDS
    bf16x8 afA0 = *(const bf16x8*)&Af[((0 + hi) * 64 +  0 + l31) * 8];
    bf16x8 afA1 = *(const bf16x8*)&Af[((0 + hi) * 64 + 32 + l31) * 8];
    bf16x8 afB0, afB1;

#pragma unroll
    for (int ks = 0; ks < 16; ++ks) {
        const int cur = ks % 3;
        const bool even = (ks & 1) == 0;

        if (ks < 14)
            bs[(ks + 2) % 3] = *(const bf16x8*)(bl + (ks + 2) * 512);
        if (ks < 15) {
            const int jn = (ks + 1) * 2 + hi;
            bf16x8 v0 = *(const bf16x8*)&Af[(jn * 64 +  0 + l31) * 8];
            bf16x8 v1 = *(const bf16x8*)&Af[(jn * 64 + 32 + l31) * 8];
            if (even) { afB0 = v0; afB1 = v1; }
            else      { afA0 = v0; afA1 = v1; }
        }

        const bf16x8 a0 = even ? afA0 : afB0;
        const bf16x8 a1 = even ? afA1 : afB1;
        // SWAPPED: C col(lane) = context row, C row(reg) = cluster
        acc0 = __builtin_amdgcn_mfma_f32_32x32x16_bf16(bs[cur], a0, acc0, 0, 0, 0);
        acc1 = __builtin_amdgcn_mfma_f32_32x32x16_bf16(bs[cur], a1, acc1, 0, 0, 0);
    }

    // aug cluster frag (prefetch before barrier)
    bf16x8 bsa = *(const bf16x8*)(bl + 16 * 512);

    __syncthreads();   // B2: context aug rows visible

    {
        bf16x8 aa0 = *(const bf16x8*)&Af[((32 + hi) * 64 +  0 + l31) * 8];
        bf16x8 aa1 = *(const bf16x8*)&Af[((32 + hi) * 64 + 32 + l31) * 8];
        acc0 = __builtin_amdgcn_mfma_f32_32x32x16_bf16(bsa, aa0, acc0, 0, 0, 0);
        acc1 = __builtin_amdgcn_mfma_f32_32x32x16_bf16(bsa, aa1, acc1, 0, 0, 0);
        // acc = 1 + d
    }

    // ---- pass 1: q = rcp(acc), IN-LANE half-row sums ----
    float s0 = 0.f, s1 = 0.f;
#pragma unroll
    for (int r = 0; r < 16; ++r) {
        acc0[r] = frcp(acc0[r]); s0 += acc0[r];
        acc1[r] = frcp(acc1[r]); s1 += acc1[r];
    }
    rowsum2[w][hi][l31]      = s0;   // row l31, this hi's 16 clusters
    rowsum2[w][hi][32 + l31] = s1;   // row 32+l31
    __syncthreads();   // B3

    // ---- pass 2: row totals, normalize, dwordx4 stores from acc ----
    float t0 = 0.f, t1 = 0.f;
#pragma unroll
    for (int q = 0; q < 8; ++q) {
        t0 += rowsum2[q][0][l31]      + rowsum2[q][1][l31];
        t1 += rowsum2[q][0][32 + l31] + rowsum2[q][1][32 + l31];
    }
    const float inv0 = frcp(t0);
    const float inv1 = frcp(t1);

    float* op0 = out + (row0 + (size_t)l31) * KC        + w * 32 + 4 * hi;
    float* op1 = out + (row0 + (size_t)(32 + l31)) * KC + w * 32 + 4 * hi;
#pragma unroll
    for (int i = 0; i < 4; ++i) {
        f32x4 v0, v1;
#pragma unroll
        for (int j = 0; j < 4; ++j) {
            v0[j] = acc0[4 * i + j] * inv0;   // cluster col = 8i + 4hi + j
            v1[j] = acc1[4 * i + j] * inv1;
        }
        *(f32x4*)(op0 + 8 * i) = v0;
        *(f32x4*)(op1 + 8 * i) = v1;
    }
}

extern "C" void kernel_launch(void* const* d_in, const int* in_sizes, int n_in,
                              void* d_out, int out_size, void* d_ws, size_t ws_size,
                              hipStream_t stream) {
    const float* ctx  = (const float*)d_in[0];
    const float* clus = (const float*)d_in[1];
    float* out = (float*)d_out;

    short* wsb = (short*)d_ws;     // cluster fragment image (8*17 KiB = 136 KiB)

    const int nrows = in_sizes[0] / DD;                      // 524288
    const int grid  = nrows / BM;                            // 8192

    hipLaunchKernelGGL(prep_clusters, dim3(KC), dim3(64), 0, stream, clus, wsb);
    hipLaunchKernelGGL(cluster_q_main, dim3(grid), dim3(512), 0, stream,
                       ctx, wsb, out);
}